// Round 1
// baseline (287.512 us; speedup 1.0000x reference)
//
#include <hip/hip_runtime.h>

// ---------------------------------------------------------------------------
// MultiheadAttention fwd, MI355X gfx950.
// B=2, S=2048, D=1024, H=16, DH=64.  Internal compute fp16 + fp32 MFMA acc.
// R4: k_attn restructured for LDS bandwidth (it was LDS-bound: 20% MfmaUtil,
// model 8.6K bank-cyc/CU-tile ~= measured 74us):
//   - 4 waves x 32 q-rows (2 groups of 16) per 256-thread block: each K/V
//     LDS read now feeds 2 q-groups -> ak/vb re-read traffic per work halves.
//   - PV uses mfma_f32_16x16x16f16: its A-fragment (4 f16/lane, k=4*qd+j)
//     matches the swapped-QK^T sacc layout exactly -> P goes MFMA->regs->MFMA,
//     the per-wave P LDS bridge (32KB traffic/blk-tile + conflicts) is GONE.
//   - V operand = conflict-free b64 reads from the swizzled vs tile.
//   - softmax scale (1/32*log2e) pre-folded into Q in k_qkv; fixed-max shift
//     dropped (cancels in softmax ratio; p <= ~4 fits f16 comfortably).
// LDS 32KB/block -> 2 blocks/CU -> 2 waves/SIMD, VGPR-capped 256.
// ---------------------------------------------------------------------------

typedef _Float16 f16;
typedef __attribute__((ext_vector_type(8))) _Float16 f16x8;
typedef __attribute__((ext_vector_type(4))) _Float16 f16x4;
typedef __attribute__((ext_vector_type(4))) float f32x4;
typedef unsigned long long u64;
typedef unsigned int u32;

#define MFMA16 __builtin_amdgcn_mfma_f32_16x16x32_f16
#define MFMA16K16 __builtin_amdgcn_mfma_f32_16x16x16f16

// ---------------- kernel 1: fp32 -> fp16 convert ---------------------------
__global__ __launch_bounds__(256) void k_convert(
    const float* __restrict__ embed, const float* __restrict__ key,
    const float* __restrict__ wq, const float* __restrict__ wk,
    const float* __restrict__ wv, const float* __restrict__ wo,
    f16* __restrict__ xe, f16* __restrict__ xk,
    f16* __restrict__ wqh, f16* __restrict__ wkh,
    f16* __restrict__ wvh, f16* __restrict__ woh)
{
    long g = (long)blockIdx.x * 256 + threadIdx.x;   // one 8-float group
    const float* src; f16* dst; long off;
    if (g < 524288)       { src = embed; dst = xe; off = g; }
    else if (g < 1048576) { src = key;   dst = xk; off = g - 524288; }
    else {
        long t = g - 1048576; int wi = (int)(t >> 17); off = t & 131071;
        if (wi == 0)      { src = wq; dst = wqh; }
        else if (wi == 1) { src = wk; dst = wkh; }
        else if (wi == 2) { src = wv; dst = wvh; }
        else              { src = wo; dst = woh; }
    }
    const float4* s4 = (const float4*)src;
    float4 a = s4[off * 2], b = s4[off * 2 + 1];
    f16x8 o;
    o[0]=(f16)a.x; o[1]=(f16)a.y; o[2]=(f16)a.z; o[3]=(f16)a.w;
    o[4]=(f16)b.x; o[5]=(f16)b.y; o[6]=(f16)b.z; o[7]=(f16)b.w;
    *(f16x8*)(dst + off * 8) = o;
}

// ---------------- kernel 2: pack attn_mask into bit words ------------------
__global__ __launch_bounds__(256) void k_packmask(
    const int* __restrict__ mask, u64* __restrict__ bits)
{
    int gw = (blockIdx.x * 256 + threadIdx.x) >> 6;   // row 0..4095
    int lane = threadIdx.x & 63;
    const int* row = mask + (long)gw * 2048;
    u64* out = bits + (long)gw * 32;
    #pragma unroll 4
    for (int c = 0; c < 32; ++c) {
        int v = row[c * 64 + lane];
        u64 b = __ballot(v != 0);
        if (lane == 0) out[c] = b;
    }
}

// ---------------- kernel 3: fused QKV GEMM ---------------------------------
__global__ __launch_bounds__(256) void k_qkv(
    const f16* __restrict__ xe, const f16* __restrict__ xk,
    const f16* __restrict__ wqh, const f16* __restrict__ wkh, const f16* __restrict__ wvh,
    const float* __restrict__ bq, const float* __restrict__ bk, const float* __restrict__ bv,
    f16* __restrict__ Qh, f16* __restrict__ Kh, f16* __restrict__ Vt)
{
    int bid = blockIdx.x;
    int which = bid >> 8;
    int rr_ = bid & 255;
    int tm = rr_ >> 3, tn = rr_ & 7;
    const f16* X = (which == 0) ? xe : xk;
    const f16* W = (which == 0) ? wqh : (which == 1) ? wkh : wvh;
    const float* bias = (which == 0) ? bq : (which == 1) ? bk : bv;

    __shared__ f16 smem[128 * 136];
    f16* la = smem;
    f16* lb = smem + 128 * 64;

    int tid = threadIdx.x;
    int lane = tid & 63, wid = tid >> 6;
    int wr = wid >> 1, wc = wid & 1;
    int lm = lane & 15, qd = lane >> 4;

    f32x4 acc[4][4];
    #pragma unroll
    for (int i = 0; i < 4; i++)
        #pragma unroll
        for (int j = 0; j < 4; j++) acc[i][j] = (f32x4)0.0f;

    int m0 = tm * 128, n0 = tn * 128;

    for (int kt = 0; kt < 16; ++kt) {
        int k0 = kt * 64;
        __syncthreads();
        #pragma unroll
        for (int t = 0; t < 4; ++t) {
            int cid = tid + t * 256;          // 0..1023 16B chunks
            int row = cid >> 3;
            int cg = cid & 7;
            int sw = cg ^ (row & 7);
            *(f16x8*)&la[row * 64 + sw * 8] =
                *(const f16x8*)&X[(long)(m0 + row) * 1024 + k0 + cg * 8];
            *(f16x8*)&lb[row * 64 + sw * 8] =
                *(const f16x8*)&W[(long)(n0 + row) * 1024 + k0 + cg * 8];
        }
        __syncthreads();
        #pragma unroll
        for (int ks = 0; ks < 2; ++ks) {
            f16x8 af[4], bfr[4];
            #pragma unroll
            for (int i = 0; i < 4; i++) {
                int m = 64 * wr + 16 * i + lm;
                int g = (ks * 4 + qd) ^ (m & 7);
                af[i] = *(const f16x8*)&la[m * 64 + g * 8];
                int n = 64 * wc + 16 * i + lm;
                int g2 = (ks * 4 + qd) ^ (n & 7);
                bfr[i] = *(const f16x8*)&lb[n * 64 + g2 * 8];
            }
            #pragma unroll
            for (int i = 0; i < 4; i++)
                #pragma unroll
                for (int j = 0; j < 4; j++)
                    acc[i][j] = MFMA16(af[i], bfr[j], acc[i][j], 0, 0, 0);
        }
    }

    if (which == 2) {
        // V: direct transposed store [B][H][64][S], b64 along s
        #pragma unroll
        for (int j = 0; j < 4; j++) {
            int n = n0 + 64 * wc + 16 * j + lm;
            float bb = bias[n];
            int h = n >> 6, d = n & 63;
            #pragma unroll
            for (int i = 0; i < 4; i++) {
                int mbase = m0 + 64 * wr + 16 * i + 4 * qd;
                f16x4 pk;
                #pragma unroll
                for (int r = 0; r < 4; ++r) pk[r] = (f16)(acc[i][j][r] + bb);
                int b = mbase >> 11, s = mbase & 2047;
                *(f16x4*)&Vt[(((long)(b * 16 + h)) * 64 + d) * 2048 + s] = pk;
            }
        }
    } else {
        // Q/K: LDS bounce -> coalesced b128 row stores.
        // Q is pre-scaled by (1/32)*log2(e) so k_attn's softmax saves a VALU
        // op per score element.
        f16* dst = (which == 0) ? Qh : Kh;
        float sc = (which == 0) ? 0.0450842252f : 1.0f;
        __syncthreads();   // all waves done reading la/lb
        #pragma unroll
        for (int j = 0; j < 4; j++) {
            int col = 64 * wc + 16 * j + lm;
            float bb = bias[n0 + col];
            #pragma unroll
            for (int i = 0; i < 4; i++) {
                int row = 64 * wr + 16 * i + 4 * qd;
                #pragma unroll
                for (int r = 0; r < 4; ++r)
                    smem[(row + r) * 136 + col] = (f16)((acc[i][j][r] + bb) * sc);
            }
        }
        __syncthreads();
        #pragma unroll
        for (int t = 0; t < 8; ++t) {
            int ci = tid + t * 256;            // 0..2047
            int row = ci >> 4, cg = ci & 15;
            f16x8 v = *(const f16x8*)&smem[row * 136 + cg * 8];
            int m = m0 + row;
            int b = m >> 11, s = m & 2047;
            int h = (n0 >> 6) + (cg >> 3);
            int d0 = (cg & 7) * 8;
            *(f16x8*)&dst[(((long)(b * 16 + h)) * 2048 + s) * 64 + d0] = v;
        }
    }
}

// ---------------- kernel 4: flash attention (S^T, reg-resident P) ----------
// 256 threads = 4 waves; each wave owns 32 q rows (2 groups of 16).
// Every K/V LDS read feeds both q-groups; PV pulls P straight from regs via
// 16x16x16 MFMA (A-fragment k=4*qd+j == sacc layout). No P LDS bridge.
__global__ __launch_bounds__(256, 2) void k_attn(
    const f16* __restrict__ Qh, const f16* __restrict__ Kh, const f16* __restrict__ Vt,
    const u64* __restrict__ mbits, f16* __restrict__ O)
{
    int bid = blockIdx.x;
    int qt = bid & 15;
    int h = (bid >> 4) & 15;
    int b = bid >> 8;
    int q0 = qt * 128;

    const f16* Qg = Qh + ((long)(b * 16 + h)) * 2048 * 64;
    const f16* Kg = Kh + ((long)(b * 16 + h)) * 2048 * 64;
    const f16* Vg = Vt + ((long)(b * 16 + h)) * 64 * 2048;

    __shared__ f16 ks[128 * 64];       // 16 KB  K tile [key][d], xor-swizzled
    __shared__ f16 vs[64 * 128];       // 16 KB  V^T tile [d][key], xor-swizzled

    int tid = threadIdx.x, lane = tid & 63, wid = tid >> 6;   // wid 0..3
    int lm = lane & 15, qd = lane >> 4;

    int qb = q0 + 32 * wid;                       // wave's 32-row q base
    const u64* Mrow0 = mbits + ((long)(b * 2048) + qb + lm) * 32;
    const u64* Mrow1 = mbits + ((long)(b * 2048) + qb + 16 + lm) * 32;

    // Q fragments (MFMA B operand), one per group per 32-d half
    f16x8 aq[2][2];
    #pragma unroll
    for (int g = 0; g < 2; ++g)
        #pragma unroll
        for (int ksi = 0; ksi < 2; ++ksi)
            aq[g][ksi] = *(const f16x8*)&Qg[(long)(qb + 16 * g + lm) * 64 + ksi * 32 + qd * 8];

    f32x4 oacc[2][4], lacc[2];
    #pragma unroll
    for (int g = 0; g < 2; ++g) {
        #pragma unroll
        for (int c = 0; c < 4; c++) oacc[g][c] = (f32x4)0.0f;
        lacc[g] = (f32x4)0.0f;
    }
    f16x4 vone4;
    #pragma unroll
    for (int j = 0; j < 4; j++) vone4[j] = (f16)1.0f;

    // u = qk_prescaled - |dist| * m * (1/32)log2e ; p = exp2(u)
    float negc2 = -__builtin_amdgcn_exp2f(-0.5f * (float)(h + 1)) * 0.0450842252f;

    for (int kt = 0; kt < 16; ++kt) {
        int k0 = kt * 128;
        __syncthreads();
        #pragma unroll
        for (int t = 0; t < 4; ++t) {
            int cid = tid + t * 256;          // 0..1023 16B chunks
            int row = cid >> 3, cg = cid & 7;
            int sw = cg ^ (row & 7);
            *(f16x8*)&ks[row * 64 + sw * 8] =
                *(const f16x8*)&Kg[(long)(k0 + row) * 64 + cg * 8];
            int vrow = cid >> 4, vg = cid & 15;
            int vsw = vg ^ (vrow & 7);
            *(f16x8*)&vs[vrow * 128 + vsw * 8] =
                *(const f16x8*)&Vg[(long)vrow * 2048 + k0 + vg * 8];
        }
        __syncthreads();

        u64 w0a = Mrow0[kt * 2], w1a = Mrow0[kt * 2 + 1];
        u64 w0b = Mrow1[kt * 2], w1b = Mrow1[kt * 2 + 1];

        // S^T = K * Q^T : sacc[g][c] is D[key=16c+4qd+r][q=lm] for group g.
        // Each ak read feeds both q-groups.
        f32x4 sacc[2][8];
        #pragma unroll
        for (int g = 0; g < 2; ++g)
            #pragma unroll
            for (int c = 0; c < 8; c++) sacc[g][c] = (f32x4)0.0f;
        #pragma unroll
        for (int ksi = 0; ksi < 2; ++ksi) {
            #pragma unroll
            for (int c = 0; c < 8; c++) {
                int kr = 16 * c + lm;
                int gg = (ksi * 4 + qd) ^ (kr & 7);
                f16x8 ak = *(const f16x8*)&ks[kr * 64 + gg * 8];
                sacc[0][c] = MFMA16(ak, aq[0][ksi], sacc[0][c], 0, 0, 0);
                sacc[1][c] = MFMA16(ak, aq[1][ksi], sacc[1][c], 0, 0, 0);
            }
        }

        // fused softmax + PV per 16-key chunk; P never leaves registers
        float qmk0 = (float)(qb + lm - k0 - 4 * qd);
        float qmk1 = qmk0 + 16.0f;
        int shb = 4 * qd;
        int vgq = qd >> 1;
        int off4 = (qd & 1) * 4;                  // f16 offset within chunk
        #pragma unroll
        for (int c = 0; c < 8; c++) {
            u32 niba = (u32)(((c < 4) ? w0a : w1a) >> (16 * (c & 3) + shb)) & 15u;
            u32 nibb = (u32)(((c < 4) ? w0b : w1b) >> (16 * (c & 3) + shb)) & 15u;
            float qc0 = qmk0 - 16.0f * (float)c;
            float qc1 = qmk1 - 16.0f * (float)c;
            f16x4 pk0, pk1;
            #pragma unroll
            for (int r = 0; r < 4; ++r) {
                float u0 = fmaf(fabsf(qc0 - (float)r), negc2, sacc[0][c][r]);
                u0 = ((niba >> r) & 1u) ? u0 : -1e30f;
                pk0[r] = (f16)__builtin_amdgcn_exp2f(u0);
                float u1 = fmaf(fabsf(qc1 - (float)r), negc2, sacc[1][c][r]);
                u1 = ((nibb >> r) & 1u) ? u1 : -1e30f;
                pk1[r] = (f16)__builtin_amdgcn_exp2f(u1);
            }
            // O += P V : K=16 MFMA, A=pk (regs), B=V^T b64 from LDS (shared
            // across both q-groups)
            int vgc = 2 * c + vgq;
            #pragma unroll
            for (int cc = 0; cc < 4; ++cc) {
                int d = 16 * cc + lm;
                f16x4 vb = *(const f16x4*)&vs[d * 128 + (vgc ^ (d & 7)) * 8 + off4];
                oacc[0][cc] = MFMA16K16(pk0, vb, oacc[0][cc], 0, 0, 0);
                oacc[1][cc] = MFMA16K16(pk1, vb, oacc[1][cc], 0, 0, 0);
            }
            lacc[0] = MFMA16K16(pk0, vone4, lacc[0], 0, 0, 0);
            lacc[1] = MFMA16K16(pk1, vone4, lacc[1], 0, 0, 0);
        }
    }

    // epilogue: rows q = qb + 16g + 4qd + r, col d = 16cc + lm
    #pragma unroll
    for (int g = 0; g < 2; ++g) {
        #pragma unroll
        for (int r = 0; r < 4; ++r) {
            float linv = 1.0f / fmaxf(lacc[g][r], 1e-30f);
            long rowbase = ((long)(b * 2048 + qb + 16 * g + 4 * qd + r)) * 1024 + h * 64;
            #pragma unroll
            for (int cc = 0; cc < 4; ++cc)
                O[rowbase + 16 * cc + lm] = (f16)(oacc[g][cc][r] * linv);
        }
    }
}

// ---------------- kernel 5: output projection ------------------------------
__global__ __launch_bounds__(256) void k_proj(
    const f16* __restrict__ Oh, const f16* __restrict__ woh,
    const float* __restrict__ bo, float* __restrict__ out)
{
    int bid = blockIdx.x;
    int tm = bid >> 3, tn = bid & 7;

    __shared__ f16 la[128 * 64];
    __shared__ f16 lb[128 * 64];

    int tid = threadIdx.x;
    int lane = tid & 63, wid = tid >> 6;
    int wr = wid >> 1, wc = wid & 1;
    int lm = lane & 15, qd = lane >> 4;

    f32x4 acc[4][4];
    #pragma unroll
    for (int i = 0; i < 4; i++)
        #pragma unroll
        for (int j = 0; j < 4; j++) acc[i][j] = (f32x4)0.0f;

    int m0 = tm * 128, n0 = tn * 128;

    for (int kt = 0; kt < 16; ++kt) {
        int k0 = kt * 64;
        __syncthreads();
        #pragma unroll
        for (int t = 0; t < 4; ++t) {
            int cid = tid + t * 256;
            int row = cid >> 3;
            int cg = cid & 7;
            int sw = cg ^ (row & 7);
            *(f16x8*)&la[row * 64 + sw * 8] =
                *(const f16x8*)&Oh[(long)(m0 + row) * 1024 + k0 + cg * 8];
            *(f16x8*)&lb[row * 64 + sw * 8] =
                *(const f16x8*)&woh[(long)(n0 + row) * 1024 + k0 + cg * 8];
        }
        __syncthreads();
        #pragma unroll
        for (int ks = 0; ks < 2; ++ks) {
            f16x8 af[4], bfr[4];
            #pragma unroll
            for (int i = 0; i < 4; i++) {
                int m = 64 * wr + 16 * i + lm;
                int g = (ks * 4 + qd) ^ (m & 7);
                af[i] = *(const f16x8*)&la[m * 64 + g * 8];
                int n = 64 * wc + 16 * i + lm;
                int g2 = (ks * 4 + qd) ^ (n & 7);
                bfr[i] = *(const f16x8*)&lb[n * 64 + g2 * 8];
            }
            #pragma unroll
            for (int i = 0; i < 4; i++)
                #pragma unroll
                for (int j = 0; j < 4; j++)
                    acc[i][j] = MFMA16(af[i], bfr[j], acc[i][j], 0, 0, 0);
        }
    }

    #pragma unroll
    for (int j = 0; j < 4; j++) {
        int n = n0 + 64 * wc + 16 * j + lm;
        float bb = bo[n];
        #pragma unroll
        for (int i = 0; i < 4; i++) {
            int mbase = m0 + 64 * wr + 16 * i + 4 * qd;
            #pragma unroll
            for (int r = 0; r < 4; ++r)
                out[(long)(mbase + r) * 1024 + n] = acc[i][j][r] + bb;
        }
    }
}

// ---------------- launch ----------------------------------------------------
extern "C" void kernel_launch(void* const* d_in, const int* in_sizes, int n_in,
                              void* d_out, int out_size, void* d_ws, size_t ws_size,
                              hipStream_t stream)
{
    const float* embed = (const float*)d_in[0];
    const float* key   = (const float*)d_in[1];
    const int*   mask  = (const int*)d_in[2];
    const float* Wq = (const float*)d_in[3];
    const float* bq = (const float*)d_in[4];
    const float* Wk = (const float*)d_in[5];
    const float* bk = (const float*)d_in[6];
    const float* Wv = (const float*)d_in[7];
    const float* bv = (const float*)d_in[8];
    const float* Wo = (const float*)d_in[9];
    const float* bo = (const float*)d_in[10];

    char* ws = (char*)d_ws;
    f16* xe  = (f16*)(ws + 0);          // 8 MB
    f16* xk  = (f16*)(ws + 8388608);    // 8 MB
    f16* wqh = (f16*)(ws + 16777216);   // 2 MB
    f16* wkh = (f16*)(ws + 18874368);
    f16* wvh = (f16*)(ws + 20971520);
    f16* woh = (f16*)(ws + 23068672);
    f16* Qh  = (f16*)(ws + 25165824);   // 8 MB  [B][H][S][64]
    f16* Kh  = (f16*)(ws + 33554432);   // 8 MB
    f16* Vt  = (f16*)(ws + 41943040);   // 8 MB  [B][H][64][S]
    f16* Oh  = (f16*)(ws + 50331648);   // 8 MB  [B*S][1024]
    u64* mb  = (u64*)(ws + 58720256);   // 1 MB
    float* out = (float*)d_out;

    k_convert<<<6144, 256, 0, stream>>>(embed, key, Wq, Wk, Wv, Wo,
                                        xe, xk, wqh, wkh, wvh, woh);
    k_packmask<<<1024, 256, 0, stream>>>(mask, mb);
    k_qkv<<<768, 256, 0, stream>>>(xe, xk, wqh, wkh, wvh, bq, bk, bv, Qh, Kh, Vt);
    k_attn<<<512, 256, 0, stream>>>(Qh, Kh, Vt, mb, Oh);
    k_proj<<<256, 256, 0, stream>>>(Oh, woh, bo, out);
}

// Round 2
// 287.265 us; speedup vs baseline: 1.0009x; 1.0009x over previous
//
#include <hip/hip_runtime.h>

// ---------------------------------------------------------------------------
// MultiheadAttention fwd, MI355X gfx950.
// B=2, S=2048, D=1024, H=16, DH=64.  Internal compute fp16 + fp32 MFMA acc.
// R5: R4 was latency-bound (occupancy 19.5%, 2 waves/SIMD, grid-limited).
// Restore 16 waves/CU while keeping R4's LDS-amortization + reg-resident P:
//   - 512-thread blocks, 8 waves: waves 0-3 do kv[0,1024), waves 4-7 do
//     kv[1024,2048); each wave owns 32 q rows (2 groups of 16) of the same
//     128-q tile. No-max softmax => partial (O,l) combine is pure addition
//     via one LDS exchange in the epilogue (no HBM partials).
//   - Staging via global_load_lds width=16: linear LDS dest + inverse-swizzled
//     per-lane global source (XOR swizzle is an involution on 16B chunks).
//   - Inner loop per 16-key chunk: sacc live range 8 regs, fits 128-VGPR cap
//     of __launch_bounds__(512,4).
//   - O written via LDS bounce -> coalesced f16x8 stores (R4's WRITE_SIZE
//     was 2.2x ideal from scalar f16 stores).
// LDS 64KB/block -> 2 blocks/CU -> 4 waves/SIMD.
// ---------------------------------------------------------------------------

typedef _Float16 f16;
typedef __attribute__((ext_vector_type(8))) _Float16 f16x8;
typedef __attribute__((ext_vector_type(4))) _Float16 f16x4;
typedef __attribute__((ext_vector_type(4))) float f32x4;
typedef unsigned long long u64;
typedef unsigned int u32;

#define MFMA16 __builtin_amdgcn_mfma_f32_16x16x32_f16
#define MFMA16K16 __builtin_amdgcn_mfma_f32_16x16x16f16

__device__ __forceinline__ void gl16(const f16* g, f16* l) {
    __builtin_amdgcn_global_load_lds(
        (const __attribute__((address_space(1))) void*)(const void*)g,
        (__attribute__((address_space(3))) void*)(void*)l,
        16, 0, 0);
}

// ---------------- kernel 1: fp32 -> fp16 convert ---------------------------
__global__ __launch_bounds__(256) void k_convert(
    const float* __restrict__ embed, const float* __restrict__ key,
    const float* __restrict__ wq, const float* __restrict__ wk,
    const float* __restrict__ wv, const float* __restrict__ wo,
    f16* __restrict__ xe, f16* __restrict__ xk,
    f16* __restrict__ wqh, f16* __restrict__ wkh,
    f16* __restrict__ wvh, f16* __restrict__ woh)
{
    long g = (long)blockIdx.x * 256 + threadIdx.x;   // one 8-float group
    const float* src; f16* dst; long off;
    if (g < 524288)       { src = embed; dst = xe; off = g; }
    else if (g < 1048576) { src = key;   dst = xk; off = g - 524288; }
    else {
        long t = g - 1048576; int wi = (int)(t >> 17); off = t & 131071;
        if (wi == 0)      { src = wq; dst = wqh; }
        else if (wi == 1) { src = wk; dst = wkh; }
        else if (wi == 2) { src = wv; dst = wvh; }
        else              { src = wo; dst = woh; }
    }
    const float4* s4 = (const float4*)src;
    float4 a = s4[off * 2], b = s4[off * 2 + 1];
    f16x8 o;
    o[0]=(f16)a.x; o[1]=(f16)a.y; o[2]=(f16)a.z; o[3]=(f16)a.w;
    o[4]=(f16)b.x; o[5]=(f16)b.y; o[6]=(f16)b.z; o[7]=(f16)b.w;
    *(f16x8*)(dst + off * 8) = o;
}

// ---------------- kernel 2: pack attn_mask into bit words ------------------
__global__ __launch_bounds__(256) void k_packmask(
    const int* __restrict__ mask, u64* __restrict__ bits)
{
    int gw = (blockIdx.x * 256 + threadIdx.x) >> 6;   // row 0..4095
    int lane = threadIdx.x & 63;
    const int* row = mask + (long)gw * 2048;
    u64* out = bits + (long)gw * 32;
    #pragma unroll 4
    for (int c = 0; c < 32; ++c) {
        int v = row[c * 64 + lane];
        u64 b = __ballot(v != 0);
        if (lane == 0) out[c] = b;
    }
}

// ---------------- kernel 3: fused QKV GEMM ---------------------------------
__global__ __launch_bounds__(256) void k_qkv(
    const f16* __restrict__ xe, const f16* __restrict__ xk,
    const f16* __restrict__ wqh, const f16* __restrict__ wkh, const f16* __restrict__ wvh,
    const float* __restrict__ bq, const float* __restrict__ bk, const float* __restrict__ bv,
    f16* __restrict__ Qh, f16* __restrict__ Kh, f16* __restrict__ Vt)
{
    int bid = blockIdx.x;
    int which = bid >> 8;
    int rr_ = bid & 255;
    int tm = rr_ >> 3, tn = rr_ & 7;
    const f16* X = (which == 0) ? xe : xk;
    const f16* W = (which == 0) ? wqh : (which == 1) ? wkh : wvh;
    const float* bias = (which == 0) ? bq : (which == 1) ? bk : bv;

    __shared__ f16 smem[128 * 136];
    f16* la = smem;
    f16* lb = smem + 128 * 64;

    int tid = threadIdx.x;
    int lane = tid & 63, wid = tid >> 6;
    int wr = wid >> 1, wc = wid & 1;
    int lm = lane & 15, qd = lane >> 4;

    f32x4 acc[4][4];
    #pragma unroll
    for (int i = 0; i < 4; i++)
        #pragma unroll
        for (int j = 0; j < 4; j++) acc[i][j] = (f32x4)0.0f;

    int m0 = tm * 128, n0 = tn * 128;

    for (int kt = 0; kt < 16; ++kt) {
        int k0 = kt * 64;
        __syncthreads();
        #pragma unroll
        for (int t = 0; t < 4; ++t) {
            int cid = tid + t * 256;          // 0..1023 16B chunks
            int row = cid >> 3;
            int cg = cid & 7;
            int sw = cg ^ (row & 7);
            *(f16x8*)&la[row * 64 + sw * 8] =
                *(const f16x8*)&X[(long)(m0 + row) * 1024 + k0 + cg * 8];
            *(f16x8*)&lb[row * 64 + sw * 8] =
                *(const f16x8*)&W[(long)(n0 + row) * 1024 + k0 + cg * 8];
        }
        __syncthreads();
        #pragma unroll
        for (int ks = 0; ks < 2; ++ks) {
            f16x8 af[4], bfr[4];
            #pragma unroll
            for (int i = 0; i < 4; i++) {
                int m = 64 * wr + 16 * i + lm;
                int g = (ks * 4 + qd) ^ (m & 7);
                af[i] = *(const f16x8*)&la[m * 64 + g * 8];
                int n = 64 * wc + 16 * i + lm;
                int g2 = (ks * 4 + qd) ^ (n & 7);
                bfr[i] = *(const f16x8*)&lb[n * 64 + g2 * 8];
            }
            #pragma unroll
            for (int i = 0; i < 4; i++)
                #pragma unroll
                for (int j = 0; j < 4; j++)
                    acc[i][j] = MFMA16(af[i], bfr[j], acc[i][j], 0, 0, 0);
        }
    }

    if (which == 2) {
        // V: direct transposed store [B][H][64][S], b64 along s
        #pragma unroll
        for (int j = 0; j < 4; j++) {
            int n = n0 + 64 * wc + 16 * j + lm;
            float bb = bias[n];
            int h = n >> 6, d = n & 63;
            #pragma unroll
            for (int i = 0; i < 4; i++) {
                int mbase = m0 + 64 * wr + 16 * i + 4 * qd;
                f16x4 pk;
                #pragma unroll
                for (int r = 0; r < 4; ++r) pk[r] = (f16)(acc[i][j][r] + bb);
                int b = mbase >> 11, s = mbase & 2047;
                *(f16x4*)&Vt[(((long)(b * 16 + h)) * 64 + d) * 2048 + s] = pk;
            }
        }
    } else {
        // Q/K: LDS bounce -> coalesced b128 row stores.
        // Q is pre-scaled by (1/32)*log2(e).
        f16* dst = (which == 0) ? Qh : Kh;
        float sc = (which == 0) ? 0.0450842252f : 1.0f;
        __syncthreads();   // all waves done reading la/lb
        #pragma unroll
        for (int j = 0; j < 4; j++) {
            int col = 64 * wc + 16 * j + lm;
            float bb = bias[n0 + col];
            #pragma unroll
            for (int i = 0; i < 4; i++) {
                int row = 64 * wr + 16 * i + 4 * qd;
                #pragma unroll
                for (int r = 0; r < 4; ++r)
                    smem[(row + r) * 136 + col] = (f16)((acc[i][j][r] + bb) * sc);
            }
        }
        __syncthreads();
        #pragma unroll
        for (int t = 0; t < 8; ++t) {
            int ci = tid + t * 256;            // 0..2047
            int row = ci >> 4, cg = ci & 15;
            f16x8 v = *(const f16x8*)&smem[row * 136 + cg * 8];
            int m = m0 + row;
            int b = m >> 11, s = m & 2047;
            int h = (n0 >> 6) + (cg >> 3);
            int d0 = (cg & 7) * 8;
            *(f16x8*)&dst[(((long)(b * 16 + h)) * 2048 + s) * 64 + d0] = v;
        }
    }
}

// ---------------- kernel 4: flash attention (S^T, kv-split, reg P) ---------
// 512 threads = 8 waves. Wave wid: q-slice = (wid&3)*32, kv-half = wid>>2.
// Each wave: 32 q rows x 1024 kv. Partials summed via LDS in epilogue
// (no-max softmax => partial O,l add exactly).
__global__ __launch_bounds__(512, 4) void k_attn(
    const f16* __restrict__ Qh, const f16* __restrict__ Kh, const f16* __restrict__ Vt,
    const u64* __restrict__ mbits, f16* __restrict__ O)
{
    int bid = blockIdx.x;
    int qt = bid & 15;
    int h = (bid >> 4) & 15;
    int b = bid >> 8;
    int q0 = qt * 128;

    const f16* Qg = Qh + ((long)(b * 16 + h)) * 2048 * 64;
    const f16* Kg = Kh + ((long)(b * 16 + h)) * 2048 * 64;
    const f16* Vg = Vt + ((long)(b * 16 + h)) * 64 * 2048;

    // 64 KB: ks0 | ks1 | vs0 | vs1, each 8192 f16 (128x64 or 64x128 swizzled)
    __shared__ f16 smem[32768];

    int tid = threadIdx.x, lane = tid & 63, wid = tid >> 6;   // wid 0..7
    int lm = lane & 15, qd = lane >> 4;
    int qs = wid & 3;          // q-slice 0..3
    int hf = wid >> 2;         // kv half 0/1

    int qb = q0 + 32 * qs;                        // wave's 32-row q base
    const u64* Mrow0 = mbits + ((long)(b * 2048) + qb + lm) * 32;
    const u64* Mrow1 = mbits + ((long)(b * 2048) + qb + 16 + lm) * 32;

    // ---- staging source precompute (linear LDS dest, inverse-swz source) --
    // wave wid stages buffer bi = wid>>1 (0,1 = K halves; 2,3 = V halves),
    // sub-half sub = wid&1 (512 chunks). 8 gload16 per wave per iteration.
    int bi = wid >> 1, sub = wid & 1;
    f16* ldst = smem + bi * 8192 + sub * 4096;    // + li*512 per load
    const f16* gE; const f16* gO; long gstep;
    if (bi < 2) {
        int krow0 = sub * 64 + (lane >> 3);
        int kcg = (lane & 7) ^ (krow0 & 7);
        gE = Kg + ((long)bi * 1024 + krow0) * 64 + kcg * 8;
        gO = gE + 512;                            // +8 rows
        gstep = 1024;                             // +16 rows per pair
    } else {
        int vh = bi - 2;
        int vrow0 = sub * 32 + (lane >> 4);
        int vgE = (lane & 15) ^ (vrow0 & 7);
        gE = Vg + (long)vrow0 * 2048 + vh * 1024 + vgE * 8;
        gO = Vg + (long)(vrow0 + 4) * 2048 + vh * 1024 + (vgE ^ 4) * 8;
        gstep = 16384;                            // +8 vrows per pair
    }
    long giter = (bi < 2) ? (long)128 * 64 : 128; // k0 += 128 per iteration

    // ---- compute-side bases ----
    const f16* ksH = smem + hf * 8192;
    const f16* vsH = smem + 16384 + hf * 8192;

    // Q fragments (MFMA B operand), per group per 32-d half
    f16x8 aq[2][2];
    #pragma unroll
    for (int g = 0; g < 2; ++g)
        #pragma unroll
        for (int ksi = 0; ksi < 2; ++ksi)
            aq[g][ksi] = *(const f16x8*)&Qg[(long)(qb + 16 * g + lm) * 64 + ksi * 32 + qd * 8];

    f32x4 oacc[2][4], lacc[2];
    #pragma unroll
    for (int g = 0; g < 2; ++g) {
        #pragma unroll
        for (int c = 0; c < 4; c++) oacc[g][c] = (f32x4)0.0f;
        lacc[g] = (f32x4)0.0f;
    }
    f16x4 vone4;
    #pragma unroll
    for (int j = 0; j < 4; j++) vone4[j] = (f16)1.0f;

    // u = qk_prescaled - |dist| * m * (1/32)log2e ; p = exp2(u)
    float negc2 = -__builtin_amdgcn_exp2f(-0.5f * (float)(h + 1)) * 0.0450842252f;

    int vgq = qd >> 1;
    int off4 = (qd & 1) * 4;
    int shb = 4 * qd;

    for (int it = 0; it < 8; ++it) {
        __syncthreads();                          // prev compute done
        #pragma unroll
        for (int p = 0; p < 4; ++p) {
            gl16(gE + p * gstep, ldst + (2 * p) * 512);
            gl16(gO + p * gstep, ldst + (2 * p + 1) * 512);
        }
        gE += giter; gO += giter;
        __syncthreads();                          // staging visible (vmcnt drained)

        int kt = hf * 8 + it;
        u64 w0a = Mrow0[kt * 2], w1a = Mrow0[kt * 2 + 1];
        u64 w0b = Mrow1[kt * 2], w1b = Mrow1[kt * 2 + 1];

        float qmk0 = (float)(qb + lm - kt * 128 - 4 * qd);
        float qmk1 = qmk0 + 16.0f;

        #pragma unroll
        for (int c = 0; c < 8; ++c) {
            // S^T = K * Q^T for this 16-key chunk, both q-groups
            int kr = 16 * c + lm;
            f32x4 s0 = (f32x4)0.0f, s1 = (f32x4)0.0f;
            #pragma unroll
            for (int ksi = 0; ksi < 2; ++ksi) {
                int gg = (ksi * 4 + qd) ^ (kr & 7);
                f16x8 ak = *(const f16x8*)&ksH[kr * 64 + gg * 8];
                s0 = MFMA16(ak, aq[0][ksi], s0, 0, 0, 0);
                s1 = MFMA16(ak, aq[1][ksi], s1, 0, 0, 0);
            }
            // softmax for the chunk (4 keys per lane at fixed q)
            u32 niba = (u32)(((c < 4) ? w0a : w1a) >> (16 * (c & 3) + shb)) & 15u;
            u32 nibb = (u32)(((c < 4) ? w0b : w1b) >> (16 * (c & 3) + shb)) & 15u;
            float qc0 = qmk0 - 16.0f * (float)c;
            float qc1 = qmk1 - 16.0f * (float)c;
            f16x4 pk0, pk1;
            #pragma unroll
            for (int r = 0; r < 4; ++r) {
                float u0 = fmaf(fabsf(qc0 - (float)r), negc2, s0[r]);
                u0 = ((niba >> r) & 1u) ? u0 : -1e30f;
                pk0[r] = (f16)__builtin_amdgcn_exp2f(u0);
                float u1 = fmaf(fabsf(qc1 - (float)r), negc2, s1[r]);
                u1 = ((nibb >> r) & 1u) ? u1 : -1e30f;
                pk1[r] = (f16)__builtin_amdgcn_exp2f(u1);
            }
            // O += P V : K=16 MFMA, A=pk (regs), B=V^T b64 from LDS
            int vgc = 2 * c + vgq;
            #pragma unroll
            for (int cc = 0; cc < 4; ++cc) {
                int d = 16 * cc + lm;
                f16x4 vb = *(const f16x4*)&vsH[d * 128 + (vgc ^ (d & 7)) * 8 + off4];
                oacc[0][cc] = MFMA16K16(pk0, vb, oacc[0][cc], 0, 0, 0);
                oacc[1][cc] = MFMA16K16(pk1, vb, oacc[1][cc], 0, 0, 0);
            }
            lacc[0] = MFMA16K16(pk0, vone4, lacc[0], 0, 0, 0);
            lacc[1] = MFMA16K16(pk1, vone4, lacc[1], 0, 0, 0);
        }
    }

    // ---- combine epilogue: half 1 -> LDS, half 0 adds, normalize, bounce ---
    __syncthreads();                              // all compute done, smem free
    float* cO = (float*)smem;                     // [4][32][64] f32, 32 KB
    float* lL = (float*)(smem + 16384);           // [4][32] f32
    f16*  fO  = smem + 16640;                     // [4][32][64] f16, 16 KB

    if (hf == 1) {
        #pragma unroll
        for (int g = 0; g < 2; ++g) {
            #pragma unroll
            for (int cc = 0; cc < 4; ++cc)
                #pragma unroll
                for (int r = 0; r < 4; ++r)
                    cO[(qs * 32 + 16 * g + 4 * qd + r) * 64 + 16 * cc + lm] = oacc[g][cc][r];
            if (lm == 0) {
                #pragma unroll
                for (int r = 0; r < 4; ++r)
                    lL[qs * 32 + 16 * g + 4 * qd + r] = lacc[g][r];
            }
        }
    }
    __syncthreads();
    if (hf == 0) {
        #pragma unroll
        for (int g = 0; g < 2; ++g) {
            float linv[4];
            #pragma unroll
            for (int r = 0; r < 4; ++r)
                linv[r] = 1.0f / fmaxf(lacc[g][r] + lL[qs * 32 + 16 * g + 4 * qd + r], 1e-30f);
            #pragma unroll
            for (int cc = 0; cc < 4; ++cc)
                #pragma unroll
                for (int r = 0; r < 4; ++r) {
                    int idx = (qs * 32 + 16 * g + 4 * qd + r) * 64 + 16 * cc + lm;
                    fO[idx] = (f16)((oacc[g][cc][r] + cO[idx]) * linv[r]);
                }
        }
    }
    __syncthreads();
    // coalesced O store: 1024 chunks of 8 f16 (rows are 128B-aligned segments)
    #pragma unroll
    for (int t = 0; t < 2; ++t) {
        int ci = tid + t * 512;                   // 0..1023
        int q = ci >> 3, dc = ci & 7;
        f16x8 v = *(const f16x8*)&fO[q * 64 + dc * 8];
        *(f16x8*)&O[((long)(b * 2048 + q0 + q)) * 1024 + h * 64 + dc * 8] = v;
    }
}

// ---------------- kernel 5: output projection ------------------------------
__global__ __launch_bounds__(256) void k_proj(
    const f16* __restrict__ Oh, const f16* __restrict__ woh,
    const float* __restrict__ bo, float* __restrict__ out)
{
    int bid = blockIdx.x;
    int tm = bid >> 3, tn = bid & 7;

    __shared__ f16 la[128 * 64];
    __shared__ f16 lb[128 * 64];

    int tid = threadIdx.x;
    int lane = tid & 63, wid = tid >> 6;
    int wr = wid >> 1, wc = wid & 1;
    int lm = lane & 15, qd = lane >> 4;

    f32x4 acc[4][4];
    #pragma unroll
    for (int i = 0; i < 4; i++)
        #pragma unroll
        for (int j = 0; j < 4; j++) acc[i][j] = (f32x4)0.0f;

    int m0 = tm * 128, n0 = tn * 128;

    for (int kt = 0; kt < 16; ++kt) {
        int k0 = kt * 64;
        __syncthreads();
        #pragma unroll
        for (int t = 0; t < 4; ++t) {
            int cid = tid + t * 256;
            int row = cid >> 3;
            int cg = cid & 7;
            int sw = cg ^ (row & 7);
            *(f16x8*)&la[row * 64 + sw * 8] =
                *(const f16x8*)&Oh[(long)(m0 + row) * 1024 + k0 + cg * 8];
            *(f16x8*)&lb[row * 64 + sw * 8] =
                *(const f16x8*)&woh[(long)(n0 + row) * 1024 + k0 + cg * 8];
        }
        __syncthreads();
        #pragma unroll
        for (int ks = 0; ks < 2; ++ks) {
            f16x8 af[4], bfr[4];
            #pragma unroll
            for (int i = 0; i < 4; i++) {
                int m = 64 * wr + 16 * i + lm;
                int g = (ks * 4 + qd) ^ (m & 7);
                af[i] = *(const f16x8*)&la[m * 64 + g * 8];
                int n = 64 * wc + 16 * i + lm;
                int g2 = (ks * 4 + qd) ^ (n & 7);
                bfr[i] = *(const f16x8*)&lb[n * 64 + g2 * 8];
            }
            #pragma unroll
            for (int i = 0; i < 4; i++)
                #pragma unroll
                for (int j = 0; j < 4; j++)
                    acc[i][j] = MFMA16(af[i], bfr[j], acc[i][j], 0, 0, 0);
        }
    }

    #pragma unroll
    for (int j = 0; j < 4; j++) {
        int n = n0 + 64 * wc + 16 * j + lm;
        float bb = bo[n];
        #pragma unroll
        for (int i = 0; i < 4; i++) {
            int mbase = m0 + 64 * wr + 16 * i + 4 * qd;
            #pragma unroll
            for (int r = 0; r < 4; ++r)
                out[(long)(mbase + r) * 1024 + n] = acc[i][j][r] + bb;
        }
    }
}

// ---------------- launch ----------------------------------------------------
extern "C" void kernel_launch(void* const* d_in, const int* in_sizes, int n_in,
                              void* d_out, int out_size, void* d_ws, size_t ws_size,
                              hipStream_t stream)
{
    const float* embed = (const float*)d_in[0];
    const float* key   = (const float*)d_in[1];
    const int*   mask  = (const int*)d_in[2];
    const float* Wq = (const float*)d_in[3];
    const float* bq = (const float*)d_in[4];
    const float* Wk = (const float*)d_in[5];
    const float* bk = (const float*)d_in[6];
    const float* Wv = (const float*)d_in[7];
    const float* bv = (const float*)d_in[8];
    const float* Wo = (const float*)d_in[9];
    const float* bo = (const float*)d_in[10];

    char* ws = (char*)d_ws;
    f16* xe  = (f16*)(ws + 0);          // 8 MB
    f16* xk  = (f16*)(ws + 8388608);    // 8 MB
    f16* wqh = (f16*)(ws + 16777216);   // 2 MB
    f16* wkh = (f16*)(ws + 18874368);
    f16* wvh = (f16*)(ws + 20971520);
    f16* woh = (f16*)(ws + 23068672);
    f16* Qh  = (f16*)(ws + 25165824);   // 8 MB  [B][H][S][64]
    f16* Kh  = (f16*)(ws + 33554432);   // 8 MB
    f16* Vt  = (f16*)(ws + 41943040);   // 8 MB  [B][H][64][S]
    f16* Oh  = (f16*)(ws + 50331648);   // 8 MB  [B*S][1024]
    u64* mb  = (u64*)(ws + 58720256);   // 1 MB
    float* out = (float*)d_out;

    k_convert<<<6144, 256, 0, stream>>>(embed, key, Wq, Wk, Wv, Wo,
                                        xe, xk, wqh, wkh, wvh, woh);
    k_packmask<<<1024, 256, 0, stream>>>(mask, mb);
    k_qkv<<<768, 256, 0, stream>>>(xe, xk, wqh, wkh, wvh, bq, bk, bv, Qh, Kh, Vt);
    k_attn<<<512, 512, 0, stream>>>(Qh, Kh, Vt, mb, Oh);
    k_proj<<<256, 256, 0, stream>>>(Oh, woh, bo, out);
}

// Round 5
// 277.140 us; speedup vs baseline: 1.0374x; 1.0365x over previous
//
#include <hip/hip_runtime.h>

// ---------------------------------------------------------------------------
// MultiheadAttention fwd, MI355X gfx950.
// B=2, S=2048, D=1024, H=16, DH=64.  Internal compute fp16 + fp32 MFMA acc.
// R8: bisect after two container failures (R6/R7, audit-clean). Base = R5
// (last passed, 287us). Changes kept from R6 (high value / low risk):
//   - k_attn 2-phase double-buffered staging (64-key subtiles, STAGE(next)
//     before compute, one barrier/iter) -> hides the 44us staging stall.
//   - XCD swizzle (bid&7)*64+(bid>>3): 4 heads' K/V (2MB) pinned per XCD L2.
//   - setprio(1) around MFMA clusters.
// Reverted from R6 (suspect surface): k_qkv/k_proj back to R5 reg-staged
// 2-barrier versions. If R8 also fails, next round = byte-exact R5.
// ---------------------------------------------------------------------------

typedef _Float16 f16;
typedef __attribute__((ext_vector_type(8))) _Float16 f16x8;
typedef __attribute__((ext_vector_type(4))) _Float16 f16x4;
typedef __attribute__((ext_vector_type(4))) float f32x4;
typedef unsigned long long u64;
typedef unsigned int u32;

#define MFMA16 __builtin_amdgcn_mfma_f32_16x16x32_f16
#define MFMA16K16 __builtin_amdgcn_mfma_f32_16x16x16f16

__device__ __forceinline__ void gl16(const f16* g, f16* l) {
    __builtin_amdgcn_global_load_lds(
        (const __attribute__((address_space(1))) void*)(const void*)g,
        (__attribute__((address_space(3))) void*)(void*)l,
        16, 0, 0);
}

// ---------------- kernel 1: fp32 -> fp16 convert ---------------------------
__global__ __launch_bounds__(256) void k_convert(
    const float* __restrict__ embed, const float* __restrict__ key,
    const float* __restrict__ wq, const float* __restrict__ wk,
    const float* __restrict__ wv, const float* __restrict__ wo,
    f16* __restrict__ xe, f16* __restrict__ xk,
    f16* __restrict__ wqh, f16* __restrict__ wkh,
    f16* __restrict__ wvh, f16* __restrict__ woh)
{
    long g = (long)blockIdx.x * 256 + threadIdx.x;   // one 8-float group
    const float* src; f16* dst; long off;
    if (g < 524288)       { src = embed; dst = xe; off = g; }
    else if (g < 1048576) { src = key;   dst = xk; off = g - 524288; }
    else {
        long t = g - 1048576; int wi = (int)(t >> 17); off = t & 131071;
        if (wi == 0)      { src = wq; dst = wqh; }
        else if (wi == 1) { src = wk; dst = wkh; }
        else if (wi == 2) { src = wv; dst = wvh; }
        else              { src = wo; dst = woh; }
    }
    const float4* s4 = (const float4*)src;
    float4 a = s4[off * 2], b = s4[off * 2 + 1];
    f16x8 o;
    o[0]=(f16)a.x; o[1]=(f16)a.y; o[2]=(f16)a.z; o[3]=(f16)a.w;
    o[4]=(f16)b.x; o[5]=(f16)b.y; o[6]=(f16)b.z; o[7]=(f16)b.w;
    *(f16x8*)(dst + off * 8) = o;
}

// ---------------- kernel 2: pack attn_mask into bit words ------------------
__global__ __launch_bounds__(256) void k_packmask(
    const int* __restrict__ mask, u64* __restrict__ bits)
{
    int gw = (blockIdx.x * 256 + threadIdx.x) >> 6;   // row 0..4095
    int lane = threadIdx.x & 63;
    const int* row = mask + (long)gw * 2048;
    u64* out = bits + (long)gw * 32;
    #pragma unroll 4
    for (int c = 0; c < 32; ++c) {
        int v = row[c * 64 + lane];
        u64 b = __ballot(v != 0);
        if (lane == 0) out[c] = b;
    }
}

// ---------------- kernel 3: fused QKV GEMM (R5 reg-staged) -----------------
__global__ __launch_bounds__(256) void k_qkv(
    const f16* __restrict__ xe, const f16* __restrict__ xk,
    const f16* __restrict__ wqh, const f16* __restrict__ wkh, const f16* __restrict__ wvh,
    const float* __restrict__ bq, const float* __restrict__ bk, const float* __restrict__ bv,
    f16* __restrict__ Qh, f16* __restrict__ Kh, f16* __restrict__ Vt)
{
    int bid = blockIdx.x;
    int which = bid >> 8;
    int rr_ = bid & 255;
    int tm = rr_ >> 3, tn = rr_ & 7;
    const f16* X = (which == 0) ? xe : xk;
    const f16* W = (which == 0) ? wqh : (which == 1) ? wkh : wvh;
    const float* bias = (which == 0) ? bq : (which == 1) ? bk : bv;

    __shared__ f16 smem[128 * 136];
    f16* la = smem;
    f16* lb = smem + 128 * 64;

    int tid = threadIdx.x;
    int lane = tid & 63, wid = tid >> 6;
    int wr = wid >> 1, wc = wid & 1;
    int lm = lane & 15, qd = lane >> 4;

    f32x4 acc[4][4];
    #pragma unroll
    for (int i = 0; i < 4; i++)
        #pragma unroll
        for (int j = 0; j < 4; j++) acc[i][j] = (f32x4)0.0f;

    int m0 = tm * 128, n0 = tn * 128;

    for (int kt = 0; kt < 16; ++kt) {
        int k0 = kt * 64;
        __syncthreads();
        #pragma unroll
        for (int t = 0; t < 4; ++t) {
            int cid = tid + t * 256;          // 0..1023 16B chunks
            int row = cid >> 3;
            int cg = cid & 7;
            int sw = cg ^ (row & 7);
            *(f16x8*)&la[row * 64 + sw * 8] =
                *(const f16x8*)&X[(long)(m0 + row) * 1024 + k0 + cg * 8];
            *(f16x8*)&lb[row * 64 + sw * 8] =
                *(const f16x8*)&W[(long)(n0 + row) * 1024 + k0 + cg * 8];
        }
        __syncthreads();
        #pragma unroll
        for (int ks = 0; ks < 2; ++ks) {
            f16x8 af[4], bfr[4];
            #pragma unroll
            for (int i = 0; i < 4; i++) {
                int m = 64 * wr + 16 * i + lm;
                int g = (ks * 4 + qd) ^ (m & 7);
                af[i] = *(const f16x8*)&la[m * 64 + g * 8];
                int n = 64 * wc + 16 * i + lm;
                int g2 = (ks * 4 + qd) ^ (n & 7);
                bfr[i] = *(const f16x8*)&lb[n * 64 + g2 * 8];
            }
            __builtin_amdgcn_s_setprio(1);
            #pragma unroll
            for (int i = 0; i < 4; i++)
                #pragma unroll
                for (int j = 0; j < 4; j++)
                    acc[i][j] = MFMA16(af[i], bfr[j], acc[i][j], 0, 0, 0);
            __builtin_amdgcn_s_setprio(0);
        }
    }

    if (which == 2) {
        // V: direct transposed store [B][H][64][S], b64 along s
        #pragma unroll
        for (int j = 0; j < 4; j++) {
            int n = n0 + 64 * wc + 16 * j + lm;
            float bb = bias[n];
            int h = n >> 6, d = n & 63;
            #pragma unroll
            for (int i = 0; i < 4; i++) {
                int mbase = m0 + 64 * wr + 16 * i + 4 * qd;
                f16x4 pk;
                #pragma unroll
                for (int r = 0; r < 4; ++r) pk[r] = (f16)(acc[i][j][r] + bb);
                int b = mbase >> 11, s = mbase & 2047;
                *(f16x4*)&Vt[(((long)(b * 16 + h)) * 64 + d) * 2048 + s] = pk;
            }
        }
    } else {
        // Q/K: LDS bounce -> coalesced b128 row stores.
        // Q pre-scaled by (1/32)*log2(e).
        f16* dst = (which == 0) ? Qh : Kh;
        float sc = (which == 0) ? 0.0450842252f : 1.0f;
        __syncthreads();   // all waves done reading la/lb
        #pragma unroll
        for (int j = 0; j < 4; j++) {
            int col = 64 * wc + 16 * j + lm;
            float bb = bias[n0 + col];
            #pragma unroll
            for (int i = 0; i < 4; i++) {
                int row = 64 * wr + 16 * i + 4 * qd;
                #pragma unroll
                for (int r = 0; r < 4; ++r)
                    smem[(row + r) * 136 + col] = (f16)((acc[i][j][r] + bb) * sc);
            }
        }
        __syncthreads();
        #pragma unroll
        for (int t = 0; t < 8; ++t) {
            int ci = tid + t * 256;            // 0..2047
            int row = ci >> 4, cg = ci & 15;
            f16x8 v = *(const f16x8*)&smem[row * 136 + cg * 8];
            int m = m0 + row;
            int b = m >> 11, s = m & 2047;
            int h = (n0 >> 6) + (cg >> 3);
            int d0 = (cg & 7) * 8;
            *(f16x8*)&dst[(((long)(b * 16 + h)) * 2048 + s) * 64 + d0] = v;
        }
    }
}

// ---------------- kernel 4: flash attention (2-phase dbuf, kv-split) -------
// 512 threads = 8 waves. Wave wid: q-slice (wid&3)*32, kv-half wid>>2.
// 64-key sub-tiles, double-buffered: STAGE(next) issued before compute(cur),
// one barrier per iter. Partial (O,l) combine via LDS (no-max softmax).
__global__ __launch_bounds__(512, 4) void k_attn(
    const f16* __restrict__ Qh, const f16* __restrict__ Kh, const f16* __restrict__ Vt,
    const u64* __restrict__ mbits, f16* __restrict__ O)
{
    int bid0 = blockIdx.x;
    int bid = (bid0 & 7) * 64 + (bid0 >> 3);      // XCD swizzle, 512 = 8*64
    int qt = bid & 15;
    int h = (bid >> 4) & 15;
    int b = bid >> 8;
    int q0 = qt * 128;

    const f16* Qg = Qh + ((long)(b * 16 + h)) * 2048 * 64;
    const f16* Kg = Kh + ((long)(b * 16 + h)) * 2048 * 64;
    const f16* Vg = Vt + ((long)(b * 16 + h)) * 64 * 2048;

    // 64 KB: 2 bufs x 16384 f16; buf: K0(4096) K1(4096) V0(4096) V1(4096)
    __shared__ f16 smem[32768];

    int tid = threadIdx.x, lane = tid & 63, wid = tid >> 6;   // wid 0..7
    int lm = lane & 15, qd = lane >> 4;
    int qs = wid & 3;          // q-slice 0..3
    int hf = wid >> 2;         // kv half 0/1

    int qb = q0 + 32 * qs;
    const u64* Mrow0 = mbits + ((long)(b * 2048) + qb + lm) * 32;
    const u64* Mrow1 = Mrow0 + 16 * 32;

    // ---- staging: wave stages bi = wid>>1 (0,1=K half; 2,3=V half),
    //      sub-half sub = wid&1; 4 gl16/wave/iter (4KB each).
    int bi = wid >> 1, sub = wid & 1;
    int rowL = lane >> 3;
    int cgL = (lane & 7) ^ rowL;
    const f16* gsrc; long lstep, istep; int doff;
    if (bi < 2) {              // K half bi: [64 key][64 d] swizzled
        gsrc = Kg + ((long)(bi * 1024 + sub * 32 + rowL)) * 64 + cgL * 8;
        lstep = 512;           // +8 key rows
        istep = 4096;          // +64 key rows per iter
        doff = bi * 4096 + sub * 2048;
    } else {                   // V half vh: V^T [64 d][64 key] swizzled
        int vh = bi - 2;
        gsrc = Vg + ((long)(sub * 32 + rowL)) * 2048 + vh * 1024 + cgL * 8;
        lstep = 16384;         // +8 d rows
        istep = 64;            // +64 keys per iter
        doff = 8192 + vh * 4096 + sub * 2048;
    }

    #define ATTN_STAGE(pb, it)                                                 \
        {                                                                      \
            f16* d0 = smem + (pb) * 16384 + doff;                              \
            const f16* s0_ = gsrc + (it) * istep;                              \
            _Pragma("unroll")                                                  \
            for (int li = 0; li < 4; ++li)                                     \
                gl16(s0_ + li * lstep, d0 + li * 512);                         \
        }

    // Q fragments (MFMA B operand), per group per 32-d half
    f16x8 aq[2][2];
    #pragma unroll
    for (int g = 0; g < 2; ++g)
        #pragma unroll
        for (int ksi = 0; ksi < 2; ++ksi)
            aq[g][ksi] = *(const f16x8*)&Qg[(long)(qb + 16 * g + lm) * 64 + ksi * 32 + qd * 8];

    f32x4 oacc[2][4], lacc[2];
    #pragma unroll
    for (int g = 0; g < 2; ++g) {
        #pragma unroll
        for (int c = 0; c < 4; c++) oacc[g][c] = (f32x4)0.0f;
        lacc[g] = (f32x4)0.0f;
    }
    f16x4 vone4;
    #pragma unroll
    for (int j = 0; j < 4; j++) vone4[j] = (f16)1.0f;

    float negc2 = -__builtin_amdgcn_exp2f(-0.5f * (float)(h + 1)) * 0.0450842252f;

    int vgq = qd >> 1;
    int off4 = (qd & 1) * 4;

    ATTN_STAGE(0, 0);
    __syncthreads();

    for (int it = 0; it < 16; ++it) {
        int pb = it & 1;
        if (it < 15) ATTN_STAGE(pb ^ 1, it + 1);

        const f16* ksH = smem + pb * 16384 + hf * 4096;
        const f16* vsH = smem + pb * 16384 + 8192 + hf * 4096;

        u64 wa = Mrow0[hf * 16 + it];
        u64 wb = Mrow1[hf * 16 + it];
        float qmk0 = (float)(qb + lm - hf * 1024 - it * 64 - 4 * qd);
        float qmk1 = qmk0 + 16.0f;

        #pragma unroll
        for (int c = 0; c < 4; ++c) {
            // S^T = K * Q^T for this 16-key chunk, both q-groups
            int kr = 16 * c + lm;
            f32x4 s0 = (f32x4)0.0f, s1 = (f32x4)0.0f;
            __builtin_amdgcn_s_setprio(1);
            #pragma unroll
            for (int ksi = 0; ksi < 2; ++ksi) {
                int gg = (ksi * 4 + qd) ^ (kr & 7);
                f16x8 ak = *(const f16x8*)&ksH[kr * 64 + gg * 8];
                s0 = MFMA16(ak, aq[0][ksi], s0, 0, 0, 0);
                s1 = MFMA16(ak, aq[1][ksi], s1, 0, 0, 0);
            }
            __builtin_amdgcn_s_setprio(0);
            // softmax (4 keys per lane at fixed q)
            u32 niba = (u32)(wa >> (16 * c + 4 * qd)) & 15u;
            u32 nibb = (u32)(wb >> (16 * c + 4 * qd)) & 15u;
            float qc0 = qmk0 - 16.0f * (float)c;
            float qc1 = qmk1 - 16.0f * (float)c;
            f16x4 pk0, pk1;
            #pragma unroll
            for (int r = 0; r < 4; ++r) {
                float u0 = fmaf(fabsf(qc0 - (float)r), negc2, s0[r]);
                u0 = ((niba >> r) & 1u) ? u0 : -1e30f;
                pk0[r] = (f16)__builtin_amdgcn_exp2f(u0);
                float u1 = fmaf(fabsf(qc1 - (float)r), negc2, s1[r]);
                u1 = ((nibb >> r) & 1u) ? u1 : -1e30f;
                pk1[r] = (f16)__builtin_amdgcn_exp2f(u1);
            }
            // O += P V : K=16 MFMA, A=pk (regs), B=V^T b64 from LDS
            int vgc = 2 * c + vgq;
            __builtin_amdgcn_s_setprio(1);
            #pragma unroll
            for (int cc = 0; cc < 4; ++cc) {
                int d = 16 * cc + lm;
                f16x4 vb = *(const f16x4*)&vsH[d * 64 + (vgc ^ (d & 7)) * 8 + off4];
                oacc[0][cc] = MFMA16K16(pk0, vb, oacc[0][cc], 0, 0, 0);
                oacc[1][cc] = MFMA16K16(pk1, vb, oacc[1][cc], 0, 0, 0);
            }
            lacc[0] = MFMA16K16(pk0, vone4, lacc[0], 0, 0, 0);
            lacc[1] = MFMA16K16(pk1, vone4, lacc[1], 0, 0, 0);
            __builtin_amdgcn_s_setprio(0);
        }
        __syncthreads();
    }
    #undef ATTN_STAGE

    // ---- combine epilogue: half 1 -> LDS, half 0 adds, normalize, bounce ---
    float* cO = (float*)smem;                     // [4][32][64] f32, 32 KB
    float* lL = (float*)(smem + 16384);           // [4][32] f32
    f16*  fO  = smem + 16640;                     // [4][32][64] f16, 16 KB

    if (hf == 1) {
        #pragma unroll
        for (int g = 0; g < 2; ++g) {
            #pragma unroll
            for (int cc = 0; cc < 4; ++cc)
                #pragma unroll
                for (int r = 0; r < 4; ++r)
                    cO[(qs * 32 + 16 * g + 4 * qd + r) * 64 + 16 * cc + lm] = oacc[g][cc][r];
            if (lm == 0) {
                #pragma unroll
                for (int r = 0; r < 4; ++r)
                    lL[qs * 32 + 16 * g + 4 * qd + r] = lacc[g][r];
            }
        }
    }
    __syncthreads();
    if (hf == 0) {
        #pragma unroll
        for (int g = 0; g < 2; ++g) {
            float linv[4];
            #pragma unroll
            for (int r = 0; r < 4; ++r)
                linv[r] = 1.0f / fmaxf(lacc[g][r] + lL[qs * 32 + 16 * g + 4 * qd + r], 1e-30f);
            #pragma unroll
            for (int cc = 0; cc < 4; ++cc)
                #pragma unroll
                for (int r = 0; r < 4; ++r) {
                    int idx = (qs * 32 + 16 * g + 4 * qd + r) * 64 + 16 * cc + lm;
                    fO[idx] = (f16)((oacc[g][cc][r] + cO[idx]) * linv[r]);
                }
        }
    }
    __syncthreads();
    // coalesced O store: 1024 chunks of 8 f16
    #pragma unroll
    for (int t = 0; t < 2; ++t) {
        int ci = tid + t * 512;                   // 0..1023
        int q = ci >> 3, dc = ci & 7;
        f16x8 v = *(const f16x8*)&fO[q * 64 + dc * 8];
        *(f16x8*)&O[((long)(b * 2048 + q0 + q)) * 1024 + h * 64 + dc * 8] = v;
    }
}

// ---------------- kernel 5: output projection (R5 reg-staged) --------------
__global__ __launch_bounds__(256) void k_proj(
    const f16* __restrict__ Oh, const f16* __restrict__ woh,
    const float* __restrict__ bo, float* __restrict__ out)
{
    int bid = blockIdx.x;
    int tm = bid >> 3, tn = bid & 7;

    __shared__ f16 la[128 * 64];
    __shared__ f16 lb[128 * 64];

    int tid = threadIdx.x;
    int lane = tid & 63, wid = tid >> 6;
    int wr = wid >> 1, wc = wid & 1;
    int lm = lane & 15, qd = lane >> 4;

    f32x4 acc[4][4];
    #pragma unroll
    for (int i = 0; i < 4; i++)
        #pragma unroll
        for (int j = 0; j < 4; j++) acc[i][j] = (f32x4)0.0f;

    int m0 = tm * 128, n0 = tn * 128;

    for (int kt = 0; kt < 16; ++kt) {
        int k0 = kt * 64;
        __syncthreads();
        #pragma unroll
        for (int t = 0; t < 4; ++t) {
            int cid = tid + t * 256;
            int row = cid >> 3;
            int cg = cid & 7;
            int sw = cg ^ (row & 7);
            *(f16x8*)&la[row * 64 + sw * 8] =
                *(const f16x8*)&Oh[(long)(m0 + row) * 1024 + k0 + cg * 8];
            *(f16x8*)&lb[row * 64 + sw * 8] =
                *(const f16x8*)&woh[(long)(n0 + row) * 1024 + k0 + cg * 8];
        }
        __syncthreads();
        #pragma unroll
        for (int ks = 0; ks < 2; ++ks) {
            f16x8 af[4], bfr[4];
            #pragma unroll
            for (int i = 0; i < 4; i++) {
                int m = 64 * wr + 16 * i + lm;
                int g = (ks * 4 + qd) ^ (m & 7);
                af[i] = *(const f16x8*)&la[m * 64 + g * 8];
                int n = 64 * wc + 16 * i + lm;
                int g2 = (ks * 4 + qd) ^ (n & 7);
                bfr[i] = *(const f16x8*)&lb[n * 64 + g2 * 8];
            }
            __builtin_amdgcn_s_setprio(1);
            #pragma unroll
            for (int i = 0; i < 4; i++)
                #pragma unroll
                for (int j = 0; j < 4; j++)
                    acc[i][j] = MFMA16(af[i], bfr[j], acc[i][j], 0, 0, 0);
            __builtin_amdgcn_s_setprio(0);
        }
    }

    #pragma unroll
    for (int j = 0; j < 4; j++) {
        int n = n0 + 64 * wc + 16 * j + lm;
        float bb = bo[n];
        #pragma unroll
        for (int i = 0; i < 4; i++) {
            int mbase = m0 + 64 * wr + 16 * i + 4 * qd;
            #pragma unroll
            for (int r = 0; r < 4; ++r)
                out[(long)(mbase + r) * 1024 + n] = acc[i][j][r] + bb;
        }
    }
}

// ---------------- launch ----------------------------------------------------
extern "C" void kernel_launch(void* const* d_in, const int* in_sizes, int n_in,
                              void* d_out, int out_size, void* d_ws, size_t ws_size,
                              hipStream_t stream)
{
    const float* embed = (const float*)d_in[0];
    const float* key   = (const float*)d_in[1];
    const int*   mask  = (const int*)d_in[2];
    const float* Wq = (const float*)d_in[3];
    const float* bq = (const float*)d_in[4];
    const float* Wk = (const float*)d_in[5];
    const float* bk = (const float*)d_in[6];
    const float* Wv = (const float*)d_in[7];
    const float* bv = (const float*)d_in[8];
    const float* Wo = (const float*)d_in[9];
    const float* bo = (const float*)d_in[10];

    char* ws = (char*)d_ws;
    f16* xe  = (f16*)(ws + 0);          // 8 MB
    f16* xk  = (f16*)(ws + 8388608);    // 8 MB
    f16* wqh = (f16*)(ws + 16777216);   // 2 MB
    f16* wkh = (f16*)(ws + 18874368);
    f16* wvh = (f16*)(ws + 20971520);
    f16* woh = (f16*)(ws + 23068672);
    f16* Qh  = (f16*)(ws + 25165824);   // 8 MB  [B][H][S][64]
    f16* Kh  = (f16*)(ws + 33554432);   // 8 MB
    f16* Vt  = (f16*)(ws + 41943040);   // 8 MB  [B][H][64][S]
    f16* Oh  = (f16*)(ws + 50331648);   // 8 MB  [B*S][1024]
    u64* mb  = (u64*)(ws + 58720256);   // 1 MB
    float* out = (float*)d_out;

    k_convert<<<6144, 256, 0, stream>>>(embed, key, Wq, Wk, Wv, Wo,
                                        xe, xk, wqh, wkh, wvh, woh);
    k_packmask<<<1024, 256, 0, stream>>>(mask, mb);
    k_qkv<<<768, 256, 0, stream>>>(xe, xk, wqh, wkh, wvh, bq, bk, bv, Qh, Kh, Vt);
    k_attn<<<512, 512, 0, stream>>>(Qh, Kh, Vt, mb, Oh);
    k_proj<<<256, 256, 0, stream>>>(Oh, woh, bo, out);
}

// Round 6
// 263.311 us; speedup vs baseline: 1.0919x; 1.0525x over previous
//
#include <hip/hip_runtime.h>

// ---------------------------------------------------------------------------
// MultiheadAttention fwd, MI355X gfx950.
// B=2, S=2048, D=1024, H=16, DH=64.  Internal compute fp16 + fp32 MFMA acc.
// R9: R8 passed (277us; k_attn 71us, FETCH 81->14MB via XCD swizzle+2phase;
// now issue-bound VALU54+MFMA34). Remaining pot = invisible ~206us (GEMMs).
//   - k_qkv/k_proj: T14 async-split dbuf reg-staging (BK=32, 2x8KB bufs):
//     {sync; issue glob->reg kt+1; ds_read+MFMA buf[pb]; sync; ds_write}.
//     Load latency hides under compute. No gl16 (container-risk bisect:
//     R6/R7 suspect stays excluded; R10 can A/B it if R9 is clean).
//   - XCD swizzle on qkv (768=8x96) and proj (256=8x32) grids: W panels
//     L2-resident per XCD (same mechanism that cut attn FETCH 5.6x).
//   - k_attn/k_convert/k_packmask byte-identical to R8.
// ---------------------------------------------------------------------------

typedef _Float16 f16;
typedef __attribute__((ext_vector_type(8))) _Float16 f16x8;
typedef __attribute__((ext_vector_type(4))) _Float16 f16x4;
typedef __attribute__((ext_vector_type(4))) float f32x4;
typedef unsigned long long u64;
typedef unsigned int u32;

#define MFMA16 __builtin_amdgcn_mfma_f32_16x16x32_f16
#define MFMA16K16 __builtin_amdgcn_mfma_f32_16x16x16f16

__device__ __forceinline__ void gl16(const f16* g, f16* l) {
    __builtin_amdgcn_global_load_lds(
        (const __attribute__((address_space(1))) void*)(const void*)g,
        (__attribute__((address_space(3))) void*)(void*)l,
        16, 0, 0);
}

// ---------------- kernel 1: fp32 -> fp16 convert ---------------------------
__global__ __launch_bounds__(256) void k_convert(
    const float* __restrict__ embed, const float* __restrict__ key,
    const float* __restrict__ wq, const float* __restrict__ wk,
    const float* __restrict__ wv, const float* __restrict__ wo,
    f16* __restrict__ xe, f16* __restrict__ xk,
    f16* __restrict__ wqh, f16* __restrict__ wkh,
    f16* __restrict__ wvh, f16* __restrict__ woh)
{
    long g = (long)blockIdx.x * 256 + threadIdx.x;   // one 8-float group
    const float* src; f16* dst; long off;
    if (g < 524288)       { src = embed; dst = xe; off = g; }
    else if (g < 1048576) { src = key;   dst = xk; off = g - 524288; }
    else {
        long t = g - 1048576; int wi = (int)(t >> 17); off = t & 131071;
        if (wi == 0)      { src = wq; dst = wqh; }
        else if (wi == 1) { src = wk; dst = wkh; }
        else if (wi == 2) { src = wv; dst = wvh; }
        else              { src = wo; dst = woh; }
    }
    const float4* s4 = (const float4*)src;
    float4 a = s4[off * 2], b = s4[off * 2 + 1];
    f16x8 o;
    o[0]=(f16)a.x; o[1]=(f16)a.y; o[2]=(f16)a.z; o[3]=(f16)a.w;
    o[4]=(f16)b.x; o[5]=(f16)b.y; o[6]=(f16)b.z; o[7]=(f16)b.w;
    *(f16x8*)(dst + off * 8) = o;
}

// ---------------- kernel 2: pack attn_mask into bit words ------------------
__global__ __launch_bounds__(256) void k_packmask(
    const int* __restrict__ mask, u64* __restrict__ bits)
{
    int gw = (blockIdx.x * 256 + threadIdx.x) >> 6;   // row 0..4095
    int lane = threadIdx.x & 63;
    const int* row = mask + (long)gw * 2048;
    u64* out = bits + (long)gw * 32;
    #pragma unroll 4
    for (int c = 0; c < 32; ++c) {
        int v = row[c * 64 + lane];
        u64 b = __ballot(v != 0);
        if (lane == 0) out[c] = b;
    }
}

// ---------------- kernel 3: fused QKV GEMM (T14 dbuf reg-staged) -----------
// BK=32, 2x8KB LDS buffers. Per iter: sync / issue loads kt+1 / compute pb /
// sync / ds_write pb^1. XCD-swizzled grid (768 = 8*96).
__global__ __launch_bounds__(256) void k_qkv(
    const f16* __restrict__ xe, const f16* __restrict__ xk,
    const f16* __restrict__ wqh, const f16* __restrict__ wkh, const f16* __restrict__ wvh,
    const float* __restrict__ bq, const float* __restrict__ bk, const float* __restrict__ bv,
    f16* __restrict__ Qh, f16* __restrict__ Kh, f16* __restrict__ Vt)
{
    int bid0 = blockIdx.x;
    int bid = (bid0 & 7) * 96 + (bid0 >> 3);      // XCD swizzle, 768 = 8*96
    int which = bid >> 8;
    int rr_ = bid & 255;
    int tm = rr_ >> 3, tn = rr_ & 7;
    const f16* X = (which == 0) ? xe : xk;
    const f16* W = (which == 0) ? wqh : (which == 1) ? wkh : wvh;
    const float* bias = (which == 0) ? bq : (which == 1) ? bk : bv;

    // 2 bufs x (la 4096 | lb 4096) = 16384 f16; Q/K bounce needs 17408 f16.
    __shared__ f16 smem[17408];

    int tid = threadIdx.x;
    int lane = tid & 63, wid = tid >> 6;
    int wr = wid >> 1, wc = wid & 1;
    int lm = lane & 15, qd = lane >> 4;

    f32x4 acc[4][4];
    #pragma unroll
    for (int i = 0; i < 4; i++)
        #pragma unroll
        for (int j = 0; j < 4; j++) acc[i][j] = (f32x4)0.0f;

    int m0 = tm * 128, n0 = tn * 128;

    // staging map: chunk ci = tid + t*256 (t=0,1) -> row = ci>>2, cg = ci&3.
    // LDS slot sw = cg ^ (row&3) (XOR swizzle for conflict-free frag reads).
    int row0 = tid >> 2, cg0 = tid & 3;
    int row1 = (tid + 256) >> 2, cg1 = (tid + 256) & 3;
    int lw0 = row0 * 32 + (cg0 ^ (row0 & 3)) * 8;
    int lw1 = row1 * 32 + (cg1 ^ (row1 & 3)) * 8;
    const f16* gx0 = X + (long)(m0 + row0) * 1024 + cg0 * 8;
    const f16* gx1 = X + (long)(m0 + row1) * 1024 + cg1 * 8;
    const f16* gw0 = W + (long)(n0 + row0) * 1024 + cg0 * 8;
    const f16* gw1 = W + (long)(n0 + row1) * 1024 + cg1 * 8;

    f16x8 rx0, rx1, rw0, rw1;
    // prologue: load tile 0, write buf 0
    rx0 = *(const f16x8*)&gx0[0];
    rx1 = *(const f16x8*)&gx1[0];
    rw0 = *(const f16x8*)&gw0[0];
    rw1 = *(const f16x8*)&gw1[0];
    *(f16x8*)&smem[lw0] = rx0;
    *(f16x8*)&smem[lw1] = rx1;
    *(f16x8*)&smem[4096 + lw0] = rw0;
    *(f16x8*)&smem[4096 + lw1] = rw1;

    for (int kt = 0; kt < 32; ++kt) {
        int pb = kt & 1;
        __syncthreads();                           // buf[pb] writes visible
        if (kt < 31) {                             // issue loads for kt+1
            int k0 = (kt + 1) * 32;
            rx0 = *(const f16x8*)&gx0[k0];
            rx1 = *(const f16x8*)&gx1[k0];
            rw0 = *(const f16x8*)&gw0[k0];
            rw1 = *(const f16x8*)&gw1[k0];
        }
        const f16* la = smem + pb * 8192;
        const f16* lb = la + 4096;
        f16x8 af[4], bfr[4];
        #pragma unroll
        for (int i = 0; i < 4; i++) {
            int m = 64 * wr + 16 * i + lm;
            af[i] = *(const f16x8*)&la[m * 32 + (qd ^ (m & 3)) * 8];
            int n = 64 * wc + 16 * i + lm;
            bfr[i] = *(const f16x8*)&lb[n * 32 + (qd ^ (n & 3)) * 8];
        }
        __builtin_amdgcn_s_setprio(1);
        #pragma unroll
        for (int i = 0; i < 4; i++)
            #pragma unroll
            for (int j = 0; j < 4; j++)
                acc[i][j] = MFMA16(af[i], bfr[j], acc[i][j], 0, 0, 0);
        __builtin_amdgcn_s_setprio(0);
        __syncthreads();                           // reads of buf[pb] done
        if (kt < 31) {
            f16* d = smem + (pb ^ 1) * 8192;
            *(f16x8*)&d[lw0] = rx0;
            *(f16x8*)&d[lw1] = rx1;
            *(f16x8*)&d[4096 + lw0] = rw0;
            *(f16x8*)&d[4096 + lw1] = rw1;
        }
    }

    if (which == 2) {
        // V: direct transposed store [B][H][64][S], b64 along s
        #pragma unroll
        for (int j = 0; j < 4; j++) {
            int n = n0 + 64 * wc + 16 * j + lm;
            float bb = bias[n];
            int h = n >> 6, d = n & 63;
            #pragma unroll
            for (int i = 0; i < 4; i++) {
                int mbase = m0 + 64 * wr + 16 * i + 4 * qd;
                f16x4 pk;
                #pragma unroll
                for (int r = 0; r < 4; ++r) pk[r] = (f16)(acc[i][j][r] + bb);
                int b = mbase >> 11, s = mbase & 2047;
                *(f16x4*)&Vt[(((long)(b * 16 + h)) * 64 + d) * 2048 + s] = pk;
            }
        }
    } else {
        // Q/K: LDS bounce -> coalesced b128 row stores.
        // Q pre-scaled by (1/32)*log2(e). Loop's final sync precedes this.
        f16* dst = (which == 0) ? Qh : Kh;
        float sc = (which == 0) ? 0.0450842252f : 1.0f;
        #pragma unroll
        for (int j = 0; j < 4; j++) {
            int col = 64 * wc + 16 * j + lm;
            float bb = bias[n0 + col];
            #pragma unroll
            for (int i = 0; i < 4; i++) {
                int row = 64 * wr + 16 * i + 4 * qd;
                #pragma unroll
                for (int r = 0; r < 4; ++r)
                    smem[(row + r) * 136 + col] = (f16)((acc[i][j][r] + bb) * sc);
            }
        }
        __syncthreads();
        #pragma unroll
        for (int t = 0; t < 8; ++t) {
            int ci = tid + t * 256;            // 0..2047
            int row = ci >> 4, cg = ci & 15;
            f16x8 v = *(const f16x8*)&smem[row * 136 + cg * 8];
            int m = m0 + row;
            int b = m >> 11, s = m & 2047;
            int h = (n0 >> 6) + (cg >> 3);
            int d0 = (cg & 7) * 8;
            *(f16x8*)&dst[(((long)(b * 16 + h)) * 2048 + s) * 64 + d0] = v;
        }
    }
}

// ---------------- kernel 4: flash attention (2-phase dbuf, kv-split) -------
// 512 threads = 8 waves. Wave wid: q-slice (wid&3)*32, kv-half wid>>2.
// 64-key sub-tiles, double-buffered: STAGE(next) issued before compute(cur),
// one barrier per iter. Partial (O,l) combine via LDS (no-max softmax).
__global__ __launch_bounds__(512, 4) void k_attn(
    const f16* __restrict__ Qh, const f16* __restrict__ Kh, const f16* __restrict__ Vt,
    const u64* __restrict__ mbits, f16* __restrict__ O)
{
    int bid0 = blockIdx.x;
    int bid = (bid0 & 7) * 64 + (bid0 >> 3);      // XCD swizzle, 512 = 8*64
    int qt = bid & 15;
    int h = (bid >> 4) & 15;
    int b = bid >> 8;
    int q0 = qt * 128;

    const f16* Qg = Qh + ((long)(b * 16 + h)) * 2048 * 64;
    const f16* Kg = Kh + ((long)(b * 16 + h)) * 2048 * 64;
    const f16* Vg = Vt + ((long)(b * 16 + h)) * 64 * 2048;

    // 64 KB: 2 bufs x 16384 f16; buf: K0(4096) K1(4096) V0(4096) V1(4096)
    __shared__ f16 smem[32768];

    int tid = threadIdx.x, lane = tid & 63, wid = tid >> 6;   // wid 0..7
    int lm = lane & 15, qd = lane >> 4;
    int qs = wid & 3;          // q-slice 0..3
    int hf = wid >> 2;         // kv half 0/1

    int qb = q0 + 32 * qs;
    const u64* Mrow0 = mbits + ((long)(b * 2048) + qb + lm) * 32;
    const u64* Mrow1 = Mrow0 + 16 * 32;

    // ---- staging: wave stages bi = wid>>1 (0,1=K half; 2,3=V half),
    //      sub-half sub = wid&1; 4 gl16/wave/iter (4KB each).
    int bi = wid >> 1, sub = wid & 1;
    int rowL = lane >> 3;
    int cgL = (lane & 7) ^ rowL;
    const f16* gsrc; long lstep, istep; int doff;
    if (bi < 2) {              // K half bi: [64 key][64 d] swizzled
        gsrc = Kg + ((long)(bi * 1024 + sub * 32 + rowL)) * 64 + cgL * 8;
        lstep = 512;           // +8 key rows
        istep = 4096;          // +64 key rows per iter
        doff = bi * 4096 + sub * 2048;
    } else {                   // V half vh: V^T [64 d][64 key] swizzled
        int vh = bi - 2;
        gsrc = Vg + ((long)(sub * 32 + rowL)) * 2048 + vh * 1024 + cgL * 8;
        lstep = 16384;         // +8 d rows
        istep = 64;            // +64 keys per iter
        doff = 8192 + vh * 4096 + sub * 2048;
    }

    #define ATTN_STAGE(pb, it)                                                 \
        {                                                                      \
            f16* d0 = smem + (pb) * 16384 + doff;                              \
            const f16* s0_ = gsrc + (it) * istep;                              \
            _Pragma("unroll")                                                  \
            for (int li = 0; li < 4; ++li)                                     \
                gl16(s0_ + li * lstep, d0 + li * 512);                         \
        }

    // Q fragments (MFMA B operand), per group per 32-d half
    f16x8 aq[2][2];
    #pragma unroll
    for (int g = 0; g < 2; ++g)
        #pragma unroll
        for (int ksi = 0; ksi < 2; ++ksi)
            aq[g][ksi] = *(const f16x8*)&Qg[(long)(qb + 16 * g + lm) * 64 + ksi * 32 + qd * 8];

    f32x4 oacc[2][4], lacc[2];
    #pragma unroll
    for (int g = 0; g < 2; ++g) {
        #pragma unroll
        for (int c = 0; c < 4; c++) oacc[g][c] = (f32x4)0.0f;
        lacc[g] = (f32x4)0.0f;
    }
    f16x4 vone4;
    #pragma unroll
    for (int j = 0; j < 4; j++) vone4[j] = (f16)1.0f;

    float negc2 = -__builtin_amdgcn_exp2f(-0.5f * (float)(h + 1)) * 0.0450842252f;

    int vgq = qd >> 1;
    int off4 = (qd & 1) * 4;

    ATTN_STAGE(0, 0);
    __syncthreads();

    for (int it = 0; it < 16; ++it) {
        int pb = it & 1;
        if (it < 15) ATTN_STAGE(pb ^ 1, it + 1);

        const f16* ksH = smem + pb * 16384 + hf * 4096;
        const f16* vsH = smem + pb * 16384 + 8192 + hf * 4096;

        u64 wa = Mrow0[hf * 16 + it];
        u64 wb = Mrow1[hf * 16 + it];
        float qmk0 = (float)(qb + lm - hf * 1024 - it * 64 - 4 * qd);
        float qmk1 = qmk0 + 16.0f;

        #pragma unroll
        for (int c = 0; c < 4; ++c) {
            // S^T = K * Q^T for this 16-key chunk, both q-groups
            int kr = 16 * c + lm;
            f32x4 s0 = (f32x4)0.0f, s1 = (f32x4)0.0f;
            __builtin_amdgcn_s_setprio(1);
            #pragma unroll
            for (int ksi = 0; ksi < 2; ++ksi) {
                int gg = (ksi * 4 + qd) ^ (kr & 7);
                f16x8 ak = *(const f16x8*)&ksH[kr * 64 + gg * 8];
                s0 = MFMA16(ak, aq[0][ksi], s0, 0, 0, 0);
                s1 = MFMA16(ak, aq[1][ksi], s1, 0, 0, 0);
            }
            __builtin_amdgcn_s_setprio(0);
            // softmax (4 keys per lane at fixed q)
            u32 niba = (u32)(wa >> (16 * c + 4 * qd)) & 15u;
            u32 nibb = (u32)(wb >> (16 * c + 4 * qd)) & 15u;
            float qc0 = qmk0 - 16.0f * (float)c;
            float qc1 = qmk1 - 16.0f * (float)c;
            f16x4 pk0, pk1;
            #pragma unroll
            for (int r = 0; r < 4; ++r) {
                float u0 = fmaf(fabsf(qc0 - (float)r), negc2, s0[r]);
                u0 = ((niba >> r) & 1u) ? u0 : -1e30f;
                pk0[r] = (f16)__builtin_amdgcn_exp2f(u0);
                float u1 = fmaf(fabsf(qc1 - (float)r), negc2, s1[r]);
                u1 = ((nibb >> r) & 1u) ? u1 : -1e30f;
                pk1[r] = (f16)__builtin_amdgcn_exp2f(u1);
            }
            // O += P V : K=16 MFMA, A=pk (regs), B=V^T b64 from LDS
            int vgc = 2 * c + vgq;
            __builtin_amdgcn_s_setprio(1);
            #pragma unroll
            for (int cc = 0; cc < 4; ++cc) {
                int d = 16 * cc + lm;
                f16x4 vb = *(const f16x4*)&vsH[d * 64 + (vgc ^ (d & 7)) * 8 + off4];
                oacc[0][cc] = MFMA16K16(pk0, vb, oacc[0][cc], 0, 0, 0);
                oacc[1][cc] = MFMA16K16(pk1, vb, oacc[1][cc], 0, 0, 0);
            }
            lacc[0] = MFMA16K16(pk0, vone4, lacc[0], 0, 0, 0);
            lacc[1] = MFMA16K16(pk1, vone4, lacc[1], 0, 0, 0);
            __builtin_amdgcn_s_setprio(0);
        }
        __syncthreads();
    }
    #undef ATTN_STAGE

    // ---- combine epilogue: half 1 -> LDS, half 0 adds, normalize, bounce ---
    float* cO = (float*)smem;                     // [4][32][64] f32, 32 KB
    float* lL = (float*)(smem + 16384);           // [4][32] f32
    f16*  fO  = smem + 16640;                     // [4][32][64] f16, 16 KB

    if (hf == 1) {
        #pragma unroll
        for (int g = 0; g < 2; ++g) {
            #pragma unroll
            for (int cc = 0; cc < 4; ++cc)
                #pragma unroll
                for (int r = 0; r < 4; ++r)
                    cO[(qs * 32 + 16 * g + 4 * qd + r) * 64 + 16 * cc + lm] = oacc[g][cc][r];
            if (lm == 0) {
                #pragma unroll
                for (int r = 0; r < 4; ++r)
                    lL[qs * 32 + 16 * g + 4 * qd + r] = lacc[g][r];
            }
        }
    }
    __syncthreads();
    if (hf == 0) {
        #pragma unroll
        for (int g = 0; g < 2; ++g) {
            float linv[4];
            #pragma unroll
            for (int r = 0; r < 4; ++r)
                linv[r] = 1.0f / fmaxf(lacc[g][r] + lL[qs * 32 + 16 * g + 4 * qd + r], 1e-30f);
            #pragma unroll
            for (int cc = 0; cc < 4; ++cc)
                #pragma unroll
                for (int r = 0; r < 4; ++r) {
                    int idx = (qs * 32 + 16 * g + 4 * qd + r) * 64 + 16 * cc + lm;
                    fO[idx] = (f16)((oacc[g][cc][r] + cO[idx]) * linv[r]);
                }
        }
    }
    __syncthreads();
    // coalesced O store: 1024 chunks of 8 f16
    #pragma unroll
    for (int t = 0; t < 2; ++t) {
        int ci = tid + t * 512;                   // 0..1023
        int q = ci >> 3, dc = ci & 7;
        f16x8 v = *(const f16x8*)&fO[q * 64 + dc * 8];
        *(f16x8*)&O[((long)(b * 2048 + q0 + q)) * 1024 + h * 64 + dc * 8] = v;
    }
}

// ---------------- kernel 5: output projection (T14 dbuf reg-staged) --------
__global__ __launch_bounds__(256) void k_proj(
    const f16* __restrict__ Oh, const f16* __restrict__ woh,
    const float* __restrict__ bo, float* __restrict__ out)
{
    int bid0 = blockIdx.x;
    int bid = (bid0 & 7) * 32 + (bid0 >> 3);      // XCD swizzle, 256 = 8*32
    int tm = bid >> 3, tn = bid & 7;

    __shared__ f16 smem[16384];   // 2 bufs x (la 4096 | lb 4096)

    int tid = threadIdx.x;
    int lane = tid & 63, wid = tid >> 6;
    int wr = wid >> 1, wc = wid & 1;
    int lm = lane & 15, qd = lane >> 4;

    f32x4 acc[4][4];
    #pragma unroll
    for (int i = 0; i < 4; i++)
        #pragma unroll
        for (int j = 0; j < 4; j++) acc[i][j] = (f32x4)0.0f;

    int m0 = tm * 128, n0 = tn * 128;

    int row0 = tid >> 2, cg0 = tid & 3;
    int row1 = (tid + 256) >> 2, cg1 = (tid + 256) & 3;
    int lw0 = row0 * 32 + (cg0 ^ (row0 & 3)) * 8;
    int lw1 = row1 * 32 + (cg1 ^ (row1 & 3)) * 8;
    const f16* gx0 = Oh  + (long)(m0 + row0) * 1024 + cg0 * 8;
    const f16* gx1 = Oh  + (long)(m0 + row1) * 1024 + cg1 * 8;
    const f16* gw0 = woh + (long)(n0 + row0) * 1024 + cg0 * 8;
    const f16* gw1 = woh + (long)(n0 + row1) * 1024 + cg1 * 8;

    f16x8 rx0, rx1, rw0, rw1;
    rx0 = *(const f16x8*)&gx0[0];
    rx1 = *(const f16x8*)&gx1[0];
    rw0 = *(const f16x8*)&gw0[0];
    rw1 = *(const f16x8*)&gw1[0];
    *(f16x8*)&smem[lw0] = rx0;
    *(f16x8*)&smem[lw1] = rx1;
    *(f16x8*)&smem[4096 + lw0] = rw0;
    *(f16x8*)&smem[4096 + lw1] = rw1;

    for (int kt = 0; kt < 32; ++kt) {
        int pb = kt & 1;
        __syncthreads();
        if (kt < 31) {
            int k0 = (kt + 1) * 32;
            rx0 = *(const f16x8*)&gx0[k0];
            rx1 = *(const f16x8*)&gx1[k0];
            rw0 = *(const f16x8*)&gw0[k0];
            rw1 = *(const f16x8*)&gw1[k0];
        }
        const f16* la = smem + pb * 8192;
        const f16* lb = la + 4096;
        f16x8 af[4], bfr[4];
        #pragma unroll
        for (int i = 0; i < 4; i++) {
            int m = 64 * wr + 16 * i + lm;
            af[i] = *(const f16x8*)&la[m * 32 + (qd ^ (m & 3)) * 8];
            int n = 64 * wc + 16 * i + lm;
            bfr[i] = *(const f16x8*)&lb[n * 32 + (qd ^ (n & 3)) * 8];
        }
        __builtin_amdgcn_s_setprio(1);
        #pragma unroll
        for (int i = 0; i < 4; i++)
            #pragma unroll
            for (int j = 0; j < 4; j++)
                acc[i][j] = MFMA16(af[i], bfr[j], acc[i][j], 0, 0, 0);
        __builtin_amdgcn_s_setprio(0);
        __syncthreads();
        if (kt < 31) {
            f16* d = smem + (pb ^ 1) * 8192;
            *(f16x8*)&d[lw0] = rx0;
            *(f16x8*)&d[lw1] = rx1;
            *(f16x8*)&d[4096 + lw0] = rw0;
            *(f16x8*)&d[4096 + lw1] = rw1;
        }
    }

    #pragma unroll
    for (int j = 0; j < 4; j++) {
        int n = n0 + 64 * wc + 16 * j + lm;
        float bb = bo[n];
        #pragma unroll
        for (int i = 0; i < 4; i++) {
            int mbase = m0 + 64 * wr + 16 * i + 4 * qd;
            #pragma unroll
            for (int r = 0; r < 4; ++r)
                out[(long)(mbase + r) * 1024 + n] = acc[i][j][r] + bb;
        }
    }
}

// ---------------- launch ----------------------------------------------------
extern "C" void kernel_launch(void* const* d_in, const int* in_sizes, int n_in,
                              void* d_out, int out_size, void* d_ws, size_t ws_size,
                              hipStream_t stream)
{
    const float* embed = (const float*)d_in[0];
    const float* key   = (const float*)d_in[1];
    const int*   mask  = (const int*)d_in[2];
    const float* Wq = (const float*)d_in[3];
    const float* bq = (const float*)d_in[4];
    const float* Wk = (const float*)d_in[5];
    const float* bk = (const float*)d_in[6];
    const float* Wv = (const float*)d_in[7];
    const float* bv = (const float*)d_in[8];
    const float* Wo = (const float*)d_in[9];
    const float* bo = (const float*)d_in[10];

    char* ws = (char*)d_ws;
    f16* xe  = (f16*)(ws + 0);          // 8 MB
    f16* xk  = (f16*)(ws + 8388608);    // 8 MB
    f16* wqh = (f16*)(ws + 16777216);   // 2 MB
    f16* wkh = (f16*)(ws + 18874368);
    f16* wvh = (f16*)(ws + 20971520);
    f16* woh = (f16*)(ws + 23068672);
    f16* Qh  = (f16*)(ws + 25165824);   // 8 MB  [B][H][S][64]
    f16* Kh  = (f16*)(ws + 33554432);   // 8 MB
    f16* Vt  = (f16*)(ws + 41943040);   // 8 MB  [B][H][64][S]
    f16* Oh  = (f16*)(ws + 50331648);   // 8 MB  [B*S][1024]
    u64* mb  = (u64*)(ws + 58720256);   // 1 MB
    float* out = (float*)d_out;

    k_convert<<<6144, 256, 0, stream>>>(embed, key, Wq, Wk, Wv, Wo,
                                        xe, xk, wqh, wkh, wvh, woh);
    k_packmask<<<1024, 256, 0, stream>>>(mask, mb);
    k_qkv<<<768, 256, 0, stream>>>(xe, xk, wqh, wkh, wvh, bq, bk, bv, Qh, Kh, Vt);
    k_attn<<<512, 512, 0, stream>>>(Qh, Kh, Vt, mb, Oh);
    k_proj<<<256, 256, 0, stream>>>(Oh, woh, bo, out);
}